// Round 1
// baseline (172.833 us; speedup 1.0000x reference)
//
#include <hip/hip_runtime.h>

// Depthwise hexagonal conv, fp32, shape (B=8, C=128, H=256, W=256).
// One wave (64 lanes) per image row; each lane computes 4 consecutive
// columns via float4. Memory-bound: target ~537 MB HBM traffic.

constexpr int Bn = 8, Cn = 128, Hn = 256, Wn = 256;

__global__ __launch_bounds__(256) void hexconv_kernel(
    const float* __restrict__ x,
    const float* __restrict__ k0,   // (C,3)
    const float* __restrict__ k1,   // (C,2,2) row-major: [c][i][j]
    const float* __restrict__ bias, // (C,)
    float* __restrict__ out)
{
    const int lane = threadIdx.x & 63;
    const int wave = threadIdx.x >> 6;
    const int rowg = blockIdx.x * 4 + wave;   // global row id in [0, B*C*H)
    const int r     = rowg & (Hn - 1);
    const int plane = rowg >> 8;              // b*C + c
    const int ch    = plane & (Cn - 1);

    // per-channel weights (L1/L2 resident, uniform per wave)
    const float k00 = k0[ch * 3 + 0];
    const float k01 = k0[ch * 3 + 1];
    const float k02 = k0[ch * 3 + 2];
    const float s00 = k1[ch * 4 + 0];  // k1[0,0]
    const float s01 = k1[ch * 4 + 1];  // k1[0,1]
    const float s10 = k1[ch * 4 + 2];  // k1[1,0]
    const float s11 = k1[ch * 4 + 3];  // k1[1,1]
    const float bv  = bias[ch];

    const size_t base = (size_t)plane * (size_t)(Hn * Wn) + (size_t)r * Wn + lane * 4;

    const float4 zero4 = make_float4(0.f, 0.f, 0.f, 0.f);
    float4 A  = (r > 0)      ? *reinterpret_cast<const float4*>(x + base - Wn) : zero4; // row r-1
    float4 Bv = *reinterpret_cast<const float4*>(x + base);                              // row r
    float4 Cv = (r < Hn - 1) ? *reinterpret_cast<const float4*>(x + base + Wn) : zero4; // row r+1

    // out-of-vector neighbors: left needs rows r (B) and r+1 (C) [even col 4l];
    // right needs rows r-1 (A) and r (B) [odd col 4l+3].
    float Bl = __shfl_up(Bv.w, 1);   if (lane == 0)  Bl = 0.f;  // x[r  ][4l-1]
    float Cl = __shfl_up(Cv.w, 1);   if (lane == 0)  Cl = 0.f;  // x[r+1][4l-1]
    float Ar = __shfl_down(A.x, 1);  if (lane == 63) Ar = 0.f;  // x[r-1][4l+4]
    float Br = __shfl_down(Bv.x, 1); if (lane == 63) Br = 0.f;  // x[r  ][4l+4]

    float4 o;
    // col 4l+0 (even): side uses rows r, r+1 at c-1 / c+1
    o.x = k00 * A.x + k01 * Bv.x + k02 * Cv.x
        + s00 * Bl   + s10 * Cl   + s01 * Bv.y + s11 * Cv.y + bv;
    // col 4l+1 (odd): side uses rows r-1, r at c-1 / c+1
    o.y = k00 * A.y + k01 * Bv.y + k02 * Cv.y
        + s00 * A.x  + s10 * Bv.x + s01 * A.z  + s11 * Bv.z + bv;
    // col 4l+2 (even)
    o.z = k00 * A.z + k01 * Bv.z + k02 * Cv.z
        + s00 * Bv.y + s10 * Cv.y + s01 * Bv.w + s11 * Cv.w + bv;
    // col 4l+3 (odd)
    o.w = k00 * A.w + k01 * Bv.w + k02 * Cv.w
        + s00 * A.z  + s10 * Bv.z + s01 * Ar   + s11 * Br   + bv;

    *reinterpret_cast<float4*>(out + base) = o;
}

extern "C" void kernel_launch(void* const* d_in, const int* in_sizes, int n_in,
                              void* d_out, int out_size, void* d_ws, size_t ws_size,
                              hipStream_t stream) {
    const float* x    = (const float*)d_in[0];
    const float* k0   = (const float*)d_in[1];
    const float* k1   = (const float*)d_in[2];
    const float* bias = (const float*)d_in[3];
    float* out        = (float*)d_out;

    const int total_rows = Bn * Cn * Hn;          // 262144
    const int blocks = total_rows / 4;            // 4 rows (waves) per block
    hexconv_kernel<<<blocks, 256, 0, stream>>>(x, k0, k1, bias, out);
}

// Round 2
// 97.597 us; speedup vs baseline: 1.7709x; 1.7709x over previous
//
#include <hip/hip_runtime.h>

// Depthwise hexagonal conv, fp32, shape (B=8, C=128, H=256, W=256).
// One wave (64 lanes) per 8-row strip; each lane owns 4 consecutive columns
// (float4). Loads R+2=10 rows into registers up front (deep MLP/ILP), computes
// R=8 rows. Memory-bound: ~537 MB minimal HBM traffic.

constexpr int Bn = 8, Cn = 128, Hn = 256, Wn = 256;
constexpr int R = 8;                       // rows per wave
constexpr int STRIPS_PER_PLANE = Hn / R;   // 32

__global__ __launch_bounds__(256) void hexconv_kernel(
    const float* __restrict__ x,
    const float* __restrict__ k0,   // (C,3)
    const float* __restrict__ k1,   // (C,2,2)
    const float* __restrict__ bias, // (C,)
    float* __restrict__ out)
{
    const int lane  = threadIdx.x & 63;
    const int wave  = threadIdx.x >> 6;
    const int strip = blockIdx.x * 4 + wave;          // [0, B*C*H/R)
    const int r0    = (strip & (STRIPS_PER_PLANE - 1)) * R;
    const int plane = strip >> 5;                     // b*C + c
    const int ch    = plane & (Cn - 1);

    const float k00 = k0[ch * 3 + 0];
    const float k01 = k0[ch * 3 + 1];
    const float k02 = k0[ch * 3 + 2];
    const float s00 = k1[ch * 4 + 0];
    const float s01 = k1[ch * 4 + 1];
    const float s10 = k1[ch * 4 + 2];
    const float s11 = k1[ch * 4 + 3];
    const float bv  = bias[ch];

    const size_t pbase = (size_t)plane * (size_t)(Hn * Wn) + (size_t)(lane * 4);
    const float4 zero4 = make_float4(0.f, 0.f, 0.f, 0.f);

    // Load rows r0-1 .. r0+R into registers (independent loads, deep ILP).
    float4 v[R + 2];
#pragma unroll
    for (int i = 0; i < R + 2; ++i) {
        const int rr = r0 - 1 + i;
        v[i] = (rr >= 0 && rr < Hn)
             ? *reinterpret_cast<const float4*>(x + pbase + (size_t)rr * Wn)
             : zero4;
    }

    // Cross-lane neighbors: left-of-vector (prev lane's .w) needed for rows in
    // B/C roles (i>=1); right-of-vector (next lane's .x) for A/B roles (i<=R).
    float lw[R + 2], rx[R + 2];
#pragma unroll
    for (int i = 1; i < R + 2; ++i) {
        lw[i] = __shfl_up(v[i].w, 1);
        if (lane == 0) lw[i] = 0.f;
    }
#pragma unroll
    for (int i = 0; i < R + 1; ++i) {
        rx[i] = __shfl_down(v[i].x, 1);
        if (lane == 63) rx[i] = 0.f;
    }

#pragma unroll
    for (int j = 0; j < R; ++j) {
        const float4 A  = v[j];       // row r-1
        const float4 Bv = v[j + 1];   // row r
        const float4 Cv = v[j + 2];   // row r+1
        const float  Bl = lw[j + 1];  // x[r  ][c0-1]
        const float  Cl = lw[j + 2];  // x[r+1][c0-1]
        const float  Ar = rx[j];      // x[r-1][c0+4]
        const float  Br = rx[j + 1];  // x[r  ][c0+4]

        float4 o;
        // col 4l+0 (even): side rows (r, r+1)
        o.x = k00 * A.x + k01 * Bv.x + k02 * Cv.x
            + s00 * Bl   + s10 * Cl   + s01 * Bv.y + s11 * Cv.y + bv;
        // col 4l+1 (odd): side rows (r-1, r)
        o.y = k00 * A.y + k01 * Bv.y + k02 * Cv.y
            + s00 * A.x  + s10 * Bv.x + s01 * A.z  + s11 * Bv.z + bv;
        // col 4l+2 (even)
        o.z = k00 * A.z + k01 * Bv.z + k02 * Cv.z
            + s00 * Bv.y + s10 * Cv.y + s01 * Bv.w + s11 * Cv.w + bv;
        // col 4l+3 (odd)
        o.w = k00 * A.w + k01 * Bv.w + k02 * Cv.w
            + s00 * A.z  + s10 * Bv.z + s01 * Ar   + s11 * Br   + bv;

        *reinterpret_cast<float4*>(out + pbase + (size_t)(r0 + j) * Wn) = o;
    }
}

extern "C" void kernel_launch(void* const* d_in, const int* in_sizes, int n_in,
                              void* d_out, int out_size, void* d_ws, size_t ws_size,
                              hipStream_t stream) {
    const float* x    = (const float*)d_in[0];
    const float* k0   = (const float*)d_in[1];
    const float* k1   = (const float*)d_in[2];
    const float* bias = (const float*)d_in[3];
    float* out        = (float*)d_out;

    const int total_strips = Bn * Cn * STRIPS_PER_PLANE;  // 32768
    const int blocks = total_strips / 4;                  // 8192 (4 waves/block)
    hexconv_kernel<<<blocks, 256, 0, stream>>>(x, k0, k1, bias, out);
}

// Round 3
// 83.429 us; speedup vs baseline: 2.0716x; 1.1698x over previous
//
#include <hip/hip_runtime.h>

// Depthwise hexagonal conv, fp32, shape (B=8, C=128, H=256, W=256).
// One wave per 8-row strip; lane owns 4 consecutive columns (float4).
// R+2 rows loaded to registers (ILP); output stored NON-TEMPORAL so the
// write stream doesn't evict the (L3-resident) input.

constexpr int Bn = 8, Cn = 128, Hn = 256, Wn = 256;
constexpr int R = 8;
constexpr int STRIPS_PER_PLANE = Hn / R;   // 32

typedef float f32x4 __attribute__((ext_vector_type(4)));

__global__ __launch_bounds__(256) void hexconv_kernel(
    const float* __restrict__ x,
    const float* __restrict__ k0,   // (C,3)
    const float* __restrict__ k1,   // (C,2,2)
    const float* __restrict__ bias, // (C,)
    float* __restrict__ out)
{
    const int lane  = threadIdx.x & 63;
    const int wave  = threadIdx.x >> 6;
    const int strip = blockIdx.x * 4 + wave;          // [0, B*C*H/R)
    const int r0    = (strip & (STRIPS_PER_PLANE - 1)) * R;
    const int plane = strip >> 5;                     // b*C + c
    const int ch    = plane & (Cn - 1);

    const float k00 = k0[ch * 3 + 0];
    const float k01 = k0[ch * 3 + 1];
    const float k02 = k0[ch * 3 + 2];
    const float s00 = k1[ch * 4 + 0];
    const float s01 = k1[ch * 4 + 1];
    const float s10 = k1[ch * 4 + 2];
    const float s11 = k1[ch * 4 + 3];
    const float bv  = bias[ch];

    const size_t pbase = (size_t)plane * (size_t)(Hn * Wn) + (size_t)(lane * 4);
    const float4 zero4 = make_float4(0.f, 0.f, 0.f, 0.f);

    // Load rows r0-1 .. r0+R into registers (independent loads, deep ILP).
    float4 v[R + 2];
#pragma unroll
    for (int i = 0; i < R + 2; ++i) {
        const int rr = r0 - 1 + i;
        v[i] = (rr >= 0 && rr < Hn)
             ? *reinterpret_cast<const float4*>(x + pbase + (size_t)rr * Wn)
             : zero4;
    }

    // Cross-lane neighbors.
    float lw[R + 2], rx[R + 2];
#pragma unroll
    for (int i = 1; i < R + 2; ++i) {
        lw[i] = __shfl_up(v[i].w, 1);
        if (lane == 0) lw[i] = 0.f;
    }
#pragma unroll
    for (int i = 0; i < R + 1; ++i) {
        rx[i] = __shfl_down(v[i].x, 1);
        if (lane == 63) rx[i] = 0.f;
    }

#pragma unroll
    for (int j = 0; j < R; ++j) {
        const float4 A  = v[j];       // row r-1
        const float4 Bv = v[j + 1];   // row r
        const float4 Cv = v[j + 2];   // row r+1
        const float  Bl = lw[j + 1];  // x[r  ][c0-1]
        const float  Cl = lw[j + 2];  // x[r+1][c0-1]
        const float  Ar = rx[j];      // x[r-1][c0+4]
        const float  Br = rx[j + 1];  // x[r  ][c0+4]

        f32x4 o;
        // col 4l+0 (even): side rows (r, r+1)
        o.x = k00 * A.x + k01 * Bv.x + k02 * Cv.x
            + s00 * Bl   + s10 * Cl   + s01 * Bv.y + s11 * Cv.y + bv;
        // col 4l+1 (odd): side rows (r-1, r)
        o.y = k00 * A.y + k01 * Bv.y + k02 * Cv.y
            + s00 * A.x  + s10 * Bv.x + s01 * A.z  + s11 * Bv.z + bv;
        // col 4l+2 (even)
        o.z = k00 * A.z + k01 * Bv.z + k02 * Cv.z
            + s00 * Bv.y + s10 * Cv.y + s01 * Bv.w + s11 * Cv.w + bv;
        // col 4l+3 (odd)
        o.w = k00 * A.w + k01 * Bv.w + k02 * Cv.w
            + s00 * A.z  + s10 * Bv.z + s01 * Ar   + s11 * Br   + bv;

        __builtin_nontemporal_store(
            o, reinterpret_cast<f32x4*>(out + pbase + (size_t)(r0 + j) * Wn));
    }
}

extern "C" void kernel_launch(void* const* d_in, const int* in_sizes, int n_in,
                              void* d_out, int out_size, void* d_ws, size_t ws_size,
                              hipStream_t stream) {
    const float* x    = (const float*)d_in[0];
    const float* k0   = (const float*)d_in[1];
    const float* k1   = (const float*)d_in[2];
    const float* bias = (const float*)d_in[3];
    float* out        = (float*)d_out;

    const int total_strips = Bn * Cn * STRIPS_PER_PLANE;  // 32768
    const int blocks = total_strips / 4;                  // 8192 (4 waves/block)
    hexconv_kernel<<<blocks, 256, 0, stream>>>(x, k0, k1, bias, out);
}